// Round 6
// baseline (35236.823 us; speedup 1.0000x reference)
//
#include <hip/hip_runtime.h>
#include <math.h>

#define NSTEP 64
#define PI_F 3.14159265358979323846f

typedef _Float16 half8 __attribute__((ext_vector_type(8)));
typedef float f32x4 __attribute__((ext_vector_type(4)));
typedef int int4v __attribute__((ext_vector_type(4)));

#define MFMA(a, b, c) __builtin_amdgcn_mfma_f32_16x16x32_f16(a, b, c, 0, 0, 0)

// ws layout in halfs: [whh0_hi 49152][whh0_lo 49152][wcat_hi 98304][wcat_lo 98304]
#define OFF_HH0_LO 49152
#define OFF_CAT_HI 98304
#define OFF_CAT_LO 196608

__device__ __forceinline__ float rcp_fast(float x) { return __builtin_amdgcn_rcpf(x); }
__device__ __forceinline__ float sigmoid_f(float x) {
    float e = __expf(-x);
    return rcp_fast(1.0f + e);
}
__device__ __forceinline__ float tanh_f(float x) {
    float ax = fabsf(x);
    float e  = __expf(-2.0f * ax);
    float t  = (1.0f - e) * rcp_fast(1.0f + e);
    return x >= 0.0f ? t : -t;
}
__device__ __forceinline__ float f16lo(int v) {
    return (float)__builtin_bit_cast(_Float16, (unsigned short)(v & 0xffff));
}
__device__ __forceinline__ float f16hi(int v) {
    return (float)__builtin_bit_cast(_Float16, (unsigned short)((unsigned)v >> 16));
}
__device__ __forceinline__ int pack_split(float f) {
    _Float16 hi = (_Float16)f;
    _Float16 lo = (_Float16)(f - (float)hi);
    return (int)__builtin_bit_cast(unsigned short, hi) |
           ((int)__builtin_bit_cast(unsigned short, lo) << 16);
}

// Prep: split fp32 weights into f16 hi/lo planes; concat [w_ih1|w_hh1] along K.
__global__ void prep_kernel(const float* __restrict__ whh0,
                            const float* __restrict__ wih1,
                            const float* __restrict__ whh1,
                            _Float16* __restrict__ wsp) {
    int i = blockIdx.x * 256 + threadIdx.x;
    if (i < 49152) {
        float v = whh0[i];
        _Float16 h = (_Float16)v;
        wsp[i] = h;
        wsp[OFF_HH0_LO + i] = (_Float16)(v - (float)h);
    }
    if (i < 98304) {
        int n = i >> 8, k = i & 255;
        float v = (k < 128) ? wih1[(n << 7) + k] : whh1[(n << 7) + k - 128];
        _Float16 h = (_Float16)v;
        wsp[OFF_CAT_HI + i] = h;
        wsp[OFF_CAT_LO + i] = (_Float16)(v - (float)h);
    }
}

__global__ void __launch_bounds__(256, 2) rnn_wf_mfma(
    const int*   __restrict__ x,
    const float* __restrict__ w_ih0,
    const float* __restrict__ w_lin,
    const float* __restrict__ b_lin,
    const _Float16* __restrict__ wsp,
    float*       __restrict__ out,
    int nbatch)
{
    __shared__ float gi0T[2][3][128];     // [bit][gate][d]
    __shared__ int   hscr[4][16 * 132];   // per-wave packed (hi|lo16) h scratch

    const int lane = threadIdx.x & 63;
    const int wv   = threadIdx.x >> 6;
    const int l4   = lane & 15;
    const int q    = lane >> 4;
    const int eBase = blockIdx.x * 64 + wv * 16;
    const int e     = eBase + l4;

    // stage gi0T: gi0T[b][g][d] = w_ih0[(g*128+d)*2 + b]
    for (int idx = threadIdx.x; idx < 768; idx += 256) {
        int b = idx / 384, rem = idx - b * 384;
        ((float*)gi0T)[b * 384 + rem] = w_ih0[rem * 2 + b];
    }
    __syncthreads();

    // ---- per-element bit mask (1 element per l4-lane) ----
    unsigned long long bm;
    {
        int ee = (e < nbatch) ? e : (nbatch - 1);
        const int* xr = x + (size_t)ee * 64 + q * 16;
        unsigned long long m = 0ull;
#pragma unroll
        for (int i = 0; i < 16; ++i)
            m |= ((unsigned long long)((unsigned)(xr[i] + 1) >> 1)) << (q * 16 + i);
        m |= __shfl_xor(m, 16);
        m |= __shfl_xor(m, 32);
        bm = m;
    }

    const _Float16* Whh0_hi = wsp;
    const _Float16* Whh0_lo = wsp + OFF_HH0_LO;
    const _Float16* Wcat_hi = wsp + OFF_CAT_HI;
    const _Float16* Wcat_lo = wsp + OFF_CAT_LO;
    const float bl0 = b_lin[0], bl1 = b_lin[1];

    // h state as B-operand fragments (hi/lo f16), [kchunk]
    // b?h[kc][j] = h[e][dim = 32*kc + 8*q + j]
    half8 b0h[4], b0l[4], b1h[4], b1l[4];
    const half8 hz = {0, 0, 0, 0, 0, 0, 0, 0};
#pragma unroll
    for (int kc = 0; kc < 4; ++kc) {
        b0h[kc] = hz; b0l[kc] = hz;
        b1h[kc] = hz; b1l[kc] = hz;
    }

    float amp = 1.0f, phs = 0.0f, nu = 0.0f, nd = 0.0f;

    for (int step = 0; step < NSTEP; ++step) {
        __syncthreads();  // phase-lock waves for L1/L2 weight reuse

        // ================= Layer 0: G^T = W_hh0 * h0^T =================
#pragma unroll
        for (int c = 0; c < 8; ++c) {
            f32x4 aR = {0, 0, 0, 0}, aZ = {0, 0, 0, 0}, aN = {0, 0, 0, 0};
#pragma unroll
            for (int kc = 0; kc < 4; ++kc) {
                int off = (16 * c + l4) * 128 + 32 * kc + 8 * q;
                half8 ahR = *(const half8*)(Whh0_hi + off);
                half8 alR = *(const half8*)(Whh0_lo + off);
                half8 ahZ = *(const half8*)(Whh0_hi + off + 128 * 128);
                half8 alZ = *(const half8*)(Whh0_lo + off + 128 * 128);
                half8 ahN = *(const half8*)(Whh0_hi + off + 256 * 128);
                half8 alN = *(const half8*)(Whh0_lo + off + 256 * 128);
                half8 bh = b0h[kc], bl = b0l[kc];
                aR = MFMA(ahR, bh, aR);
                aZ = MFMA(ahZ, bh, aZ);
                aN = MFMA(ahN, bh, aN);
                aR = MFMA(ahR, bl, aR);
                aZ = MFMA(ahZ, bl, aZ);
                aN = MFMA(ahN, bl, aN);
                aR = MFMA(alR, bh, aR);
                aZ = MFMA(alZ, bh, aZ);
                aN = MFMA(alN, bh, aN);
            }
            // ---- epilogue: rows d = 16c + 4q + r ----
            f32x4 giR = {0, 0, 0, 0}, giZ = {0, 0, 0, 0}, giN = {0, 0, 0, 0};
            if (step > 0) {
                int pb = (int)((bm >> (step - 1)) & 1ull);
                const float* gp = &gi0T[pb][0][0];
                int d0 = 16 * c + 4 * q;
                giR = *(const f32x4*)(gp + d0);
                giZ = *(const f32x4*)(gp + 128 + d0);
                giN = *(const f32x4*)(gp + 256 + d0);
            }
            // h0_prev[d][e]: dim d lives in frag kc=c>>1 on lane (q'=2c+(q>>1) mod 4, l4=e),
            // register j = 4*(q&1)+r. Shuffle whole frag, select locally.
            {
                int4v Hh = __builtin_bit_cast(int4v, b0h[c >> 1]);
                int4v Hl = __builtin_bit_cast(int4v, b0l[c >> 1]);
                int src = (((2 * c + (q >> 1)) & 3) << 4) | l4;
                int h0s = __shfl(Hh[0], src), h1s = __shfl(Hh[1], src);
                int h2s = __shfl(Hh[2], src), h3s = __shfl(Hh[3], src);
                int g0s = __shfl(Hl[0], src), g1s = __shfl(Hl[1], src);
                int g2s = __shfl(Hl[2], src), g3s = __shfl(Hl[3], src);
                int qodd = q & 1;
                int ah0 = qodd ? h2s : h0s;
                int ah1 = qodd ? h3s : h1s;
                int al0 = qodd ? g2s : g0s;
                int al1 = qodd ? g3s : g1s;
                float hp[4];
                hp[0] = f16lo(ah0) + f16lo(al0);
                hp[1] = f16hi(ah0) + f16hi(al0);
                hp[2] = f16lo(ah1) + f16lo(al1);
                hp[3] = f16hi(ah1) + f16hi(al1);

                int4v pk;
#pragma unroll
                for (int r = 0; r < 4; ++r) {
                    float rr = sigmoid_f(giR[r] + aR[r]);
                    float zz = sigmoid_f(giZ[r] + aZ[r]);
                    float nn = tanh_f(giN[r] + rr * aN[r]);
                    float hn = (1.0f - zz) * nn + zz * hp[r];
                    pk[r] = pack_split(hn);
                }
                *(int4v*)&hscr[wv][l4 * 132 + 16 * c + 4 * q] = pk;
            }
        }
        // rebuild h0 B-frags from scratch
#pragma unroll
        for (int kc = 0; kc < 4; ++kc) {
            const int4v* p = (const int4v*)&hscr[wv][l4 * 132 + 32 * kc + 8 * q];
            int4v p0 = p[0], p1 = p[1];
            int4v hi, lo;
            hi[0] = (p0[0] & 0xffff) | (p0[1] << 16);
            hi[1] = (p0[2] & 0xffff) | (p0[3] << 16);
            hi[2] = (p1[0] & 0xffff) | (p1[1] << 16);
            hi[3] = (p1[2] & 0xffff) | (p1[3] << 16);
            lo[0] = (int)(((unsigned)p0[0]) >> 16) | (p0[1] & 0xffff0000);
            lo[1] = (int)(((unsigned)p0[2]) >> 16) | (p0[3] & 0xffff0000);
            lo[2] = (int)(((unsigned)p1[0]) >> 16) | (p1[1] & 0xffff0000);
            lo[3] = (int)(((unsigned)p1[2]) >> 16) | (p1[3] & 0xffff0000);
            b0h[kc] = __builtin_bit_cast(half8, hi);
            b0l[kc] = __builtin_bit_cast(half8, lo);
        }

        __syncthreads();

        // ===== Layer 1: G^T = [Wih1|Whh1] * [h0;h1]^T, N-gate split =====
        float l0p = 0.0f, l1p = 0.0f;
#pragma unroll
        for (int c = 0; c < 8; ++c) {
            f32x4 aR = {0, 0, 0, 0}, aZ = {0, 0, 0, 0};
            f32x4 aNi = {0, 0, 0, 0}, aNh = {0, 0, 0, 0};
#pragma unroll
            for (int kc = 0; kc < 8; ++kc) {
                int off = (16 * c + l4) * 256 + 32 * kc + 8 * q;
                half8 ahR = *(const half8*)(Wcat_hi + off);
                half8 alR = *(const half8*)(Wcat_lo + off);
                half8 ahZ = *(const half8*)(Wcat_hi + off + 128 * 256);
                half8 alZ = *(const half8*)(Wcat_lo + off + 128 * 256);
                half8 ahN = *(const half8*)(Wcat_hi + off + 256 * 256);
                half8 alN = *(const half8*)(Wcat_lo + off + 256 * 256);
                half8 bh = (kc < 4) ? b0h[kc] : b1h[kc - 4];
                half8 bl = (kc < 4) ? b0l[kc] : b1l[kc - 4];
                aR = MFMA(ahR, bh, aR);
                aZ = MFMA(ahZ, bh, aZ);
                aR = MFMA(ahR, bl, aR);
                aZ = MFMA(ahZ, bl, aZ);
                aR = MFMA(alR, bh, aR);
                aZ = MFMA(alZ, bh, aZ);
                if (kc < 4) {
                    aNi = MFMA(ahN, bh, aNi);
                    aNi = MFMA(ahN, bl, aNi);
                    aNi = MFMA(alN, bh, aNi);
                } else {
                    aNh = MFMA(ahN, bh, aNh);
                    aNh = MFMA(ahN, bl, aNh);
                    aNh = MFMA(alN, bh, aNh);
                }
            }
            {
                int4v Hh = __builtin_bit_cast(int4v, b1h[c >> 1]);
                int4v Hl = __builtin_bit_cast(int4v, b1l[c >> 1]);
                int src = (((2 * c + (q >> 1)) & 3) << 4) | l4;
                int h0s = __shfl(Hh[0], src), h1s = __shfl(Hh[1], src);
                int h2s = __shfl(Hh[2], src), h3s = __shfl(Hh[3], src);
                int g0s = __shfl(Hl[0], src), g1s = __shfl(Hl[1], src);
                int g2s = __shfl(Hl[2], src), g3s = __shfl(Hl[3], src);
                int qodd = q & 1;
                int ah0 = qodd ? h2s : h0s;
                int ah1 = qodd ? h3s : h1s;
                int al0 = qodd ? g2s : g0s;
                int al1 = qodd ? g3s : g1s;
                float hp[4];
                hp[0] = f16lo(ah0) + f16lo(al0);
                hp[1] = f16hi(ah0) + f16hi(al0);
                hp[2] = f16lo(ah1) + f16lo(al1);
                hp[3] = f16hi(ah1) + f16hi(al1);

                f32x4 wl0 = *(const f32x4*)(w_lin + 16 * c + 4 * q);
                f32x4 wl1 = *(const f32x4*)(w_lin + 128 + 16 * c + 4 * q);
                int4v pk;
#pragma unroll
                for (int r = 0; r < 4; ++r) {
                    float rr = sigmoid_f(aR[r]);
                    float zz = sigmoid_f(aZ[r]);
                    float nn = tanh_f(aNi[r] + rr * aNh[r]);
                    float hn = (1.0f - zz) * nn + zz * hp[r];
                    l0p = fmaf(hn, wl0[r], l0p);
                    l1p = fmaf(hn, wl1[r], l1p);
                    pk[r] = pack_split(hn);
                }
                *(int4v*)&hscr[wv][l4 * 132 + 16 * c + 4 * q] = pk;
            }
        }
        // rebuild h1 B-frags
#pragma unroll
        for (int kc = 0; kc < 4; ++kc) {
            const int4v* p = (const int4v*)&hscr[wv][l4 * 132 + 32 * kc + 8 * q];
            int4v p0 = p[0], p1 = p[1];
            int4v hi, lo;
            hi[0] = (p0[0] & 0xffff) | (p0[1] << 16);
            hi[1] = (p0[2] & 0xffff) | (p0[3] << 16);
            hi[2] = (p1[0] & 0xffff) | (p1[1] << 16);
            hi[3] = (p1[2] & 0xffff) | (p1[3] << 16);
            lo[0] = (int)(((unsigned)p0[0]) >> 16) | (p0[1] & 0xffff0000);
            lo[1] = (int)(((unsigned)p0[2]) >> 16) | (p0[3] & 0xffff0000);
            lo[2] = (int)(((unsigned)p1[0]) >> 16) | (p1[1] & 0xffff0000);
            lo[3] = (int)(((unsigned)p1[2]) >> 16) | (p1[3] & 0xffff0000);
            b1h[kc] = __builtin_bit_cast(half8, hi);
            b1l[kc] = __builtin_bit_cast(half8, lo);
        }

        // ================= head =================
        {
            float l0 = l0p;
            l0 += __shfl_xor(l0, 16); l0 += __shfl_xor(l0, 32); l0 += bl0;
            float l1 = l1p;
            l1 += __shfl_xor(l1, 16); l1 += __shfl_xor(l1, 32); l1 += bl1;

            float p0 = sigmoid_f(l0 - l1);
            float p1 = sigmoid_f(l1 - l0);
            float y0 = sqrtf(p0), y1 = sqrtf(p1);
            float ph0 = PI_F * l0 * rcp_fast(1.0f + fabsf(l0));
            float ph1 = PI_F * l1 * rcp_fast(1.0f + fabsf(l1));

            int bit = (int)((bm >> step) & 1ull);
            bool is_even = (step & 1) == 0;
            float num   = is_even ? nu : nd;
            float lower = -16.0f + (float)(step >> 1);
            float occ   = (num < 16.0f) ? 1.0f : 0.0f;
            float unocc = (num > lower) ? 1.0f : 0.0f;
            if (step >= 16) {
                float m0 = y0 * unocc, m1 = y1 * occ;
                float nrm = fmaxf(sqrtf(m0 * m0 + m1 * m1), 1e-12f);
                float rn  = rcp_fast(nrm);
                y0 = m0 * rn; y1 = m1 * rn;
            }
            if (is_even) nu += (float)bit; else nd += (float)bit;
            amp *= bit ? y1 : y0;
            phs += bit ? ph1 : ph0;
        }
    }

    if (q == 0 && e < nbatch) {
        float s, c;
        sincosf(phs, &s, &c);
        out[e]          = amp * c;
        out[nbatch + e] = amp * s;
    }
}

extern "C" void kernel_launch(void* const* d_in, const int* in_sizes, int n_in,
                              void* d_out, int out_size, void* d_ws, size_t ws_size,
                              hipStream_t stream) {
    const int*   x     = (const int*)  d_in[0];
    const float* w_ih0 = (const float*)d_in[1];
    const float* w_hh0 = (const float*)d_in[2];
    const float* w_ih1 = (const float*)d_in[3];
    const float* w_hh1 = (const float*)d_in[4];
    const float* w_lin = (const float*)d_in[5];
    const float* b_lin = (const float*)d_in[6];
    float* out = (float*)d_out;
    _Float16* wsp = (_Float16*)d_ws;

    const int nbatch = in_sizes[0] / 64;

    prep_kernel<<<384, 256, 0, stream>>>(w_hh0, w_ih1, w_hh1, wsp);

    const int blocks = (nbatch + 63) / 64;
    rnn_wf_mfma<<<blocks, 256, 0, stream>>>(x, w_ih0, w_lin, b_lin, wsp, out, nbatch);
}

// Round 7
// 3908.800 us; speedup vs baseline: 9.0147x; 9.0147x over previous
//
#include <hip/hip_runtime.h>
#include <math.h>

#define NSTEP 64
#define PI_F 3.14159265358979323846f

typedef _Float16 half8 __attribute__((ext_vector_type(8)));
typedef _Float16 half4 __attribute__((ext_vector_type(4)));
typedef float f32x4 __attribute__((ext_vector_type(4)));

#define MFMA(a, b, c) __builtin_amdgcn_mfma_f32_16x16x32_f16(a, b, c, 0, 0, 0)

#define OFF_CAT 49152   // halfs: wcat starts after whh0 (3*128*128)
#define HROW 136        // f16 row stride for h planes (128 + pad), 272 B

__device__ __forceinline__ float rcp_fast(float x) { return __builtin_amdgcn_rcpf(x); }
__device__ __forceinline__ float sigmoid_f(float x) {
    float e = __expf(-x);
    return rcp_fast(1.0f + e);
}
__device__ __forceinline__ float tanh_f(float x) {
    float ax = fabsf(x);
    float e  = __expf(-2.0f * ax);
    float t  = (1.0f - e) * rcp_fast(1.0f + e);
    return x >= 0.0f ? t : -t;
}

// Prep: f16 (hi-plane only) weights; concat [w_ih1|w_hh1] along K for layer 1.
__global__ void prep_kernel(const float* __restrict__ whh0,
                            const float* __restrict__ wih1,
                            const float* __restrict__ whh1,
                            _Float16* __restrict__ wsp) {
    int i = blockIdx.x * 256 + threadIdx.x;
    if (i < 49152) wsp[i] = (_Float16)whh0[i];
    if (i < 98304) {
        int n = i >> 8, k = i & 255;
        float v = (k < 128) ? wih1[(n << 7) + k] : whh1[(n << 7) + k - 128];
        wsp[OFF_CAT + i] = (_Float16)v;
    }
}

__global__ void __launch_bounds__(512, 2) rnn_wf_pers(
    const int*   __restrict__ x,
    const float* __restrict__ w_ih0,
    const float* __restrict__ w_lin,
    const float* __restrict__ b_lin,
    const _Float16* __restrict__ wsp,
    float*       __restrict__ out,
    int nbatch)
{
    // h state: separate hi/lo f16 planes, [element][dim] with padded rows
    __shared__ _Float16 h0hi[128][HROW], h0lo[128][HROW];
    __shared__ _Float16 h1hi[128][HROW], h1lo[128][HROW];
    __shared__ float gi0T[2][3][128];          // [prev-bit][gate][dim]
    __shared__ float lsc[2][128][8];           // logit partials [logit][e][wave]
    __shared__ unsigned long long bmk[128];    // per-element bit mask

    const int t    = threadIdx.x;
    const int wv   = t >> 6;        // wave 0..7 -> owns dims [16wv, 16wv+16) per gate
    const int lane = t & 63;
    const int l4   = lane & 15;
    const int q    = lane >> 4;
    const int eb   = blockIdx.x * 128;

    // ---- init LDS ----
    for (int i = t; i < 128 * HROW; i += 512) {
        ((_Float16*)h0hi)[i] = (_Float16)0.0f; ((_Float16*)h0lo)[i] = (_Float16)0.0f;
        ((_Float16*)h1hi)[i] = (_Float16)0.0f; ((_Float16*)h1lo)[i] = (_Float16)0.0f;
    }
    for (int i = t; i < 768; i += 512) {
        int b = i / 384, rem = i - b * 384;
        ((float*)gi0T)[b * 384 + rem] = w_ih0[rem * 2 + b];   // gi0T[b][g][d]
    }
    {   // bit masks: thread t -> element t>>2, quarter t&3
        int el = t >> 2, qq = t & 3;
        int eg = eb + el; if (eg >= nbatch) eg = nbatch - 1;
        const int* xr = x + (size_t)eg * 64 + qq * 16;
        unsigned long long m = 0ull;
#pragma unroll
        for (int i = 0; i < 16; ++i)
            m |= ((unsigned long long)((unsigned)(xr[i] + 1) >> 1)) << (qq * 16 + i);
        m |= __shfl_xor(m, 1);
        m |= __shfl_xor(m, 2);
        if (qq == 0) bmk[el] = m;
    }

    // ---- persistent weight fragments in registers ----
    // A-frag for row m = 16wv + l4 of gate g, k-chunk kc: w[(g*128+16wv+l4)][32kc+8q .. +8]
    half8 wl0[3][4], wl1[3][8];
    {
        const _Float16* p0 = wsp;
#pragma unroll
        for (int g = 0; g < 3; ++g)
#pragma unroll
            for (int kc = 0; kc < 4; ++kc)
                wl0[g][kc] = *(const half8*)(p0 + (size_t)(g * 128 + 16 * wv + l4) * 128 + 32 * kc + 8 * q);
        const _Float16* p1 = wsp + OFF_CAT;
#pragma unroll
        for (int g = 0; g < 3; ++g)
#pragma unroll
            for (int kc = 0; kc < 8; ++kc)
                wl1[g][kc] = *(const half8*)(p1 + (size_t)(g * 128 + 16 * wv + l4) * 256 + 32 * kc + 8 * q);
    }
    const int d0 = 16 * wv + 4 * q;            // first of 4 dims this lane updates
    const f32x4 wlin0 = *(const f32x4*)(w_lin + d0);
    const f32x4 wlin1 = *(const f32x4*)(w_lin + 128 + d0);
    const float bl0 = b_lin[0], bl1 = b_lin[1];

    // head state for element eh = 16wv + l4 (replicated across q)
    const int eh = 16 * wv + l4;
    float amp = 1.0f, phs = 0.0f, nu = 0.0f, nd = 0.0f;

    half4 sh[8], sl[8];   // staging for new-h (hi/lo), 8 n-tiles

    __syncthreads();

    for (int step = 0; step < NSTEP; ++step) {
        // ================= Layer 0: rows 16wv..16wv+16 per gate =================
#pragma unroll
        for (int n = 0; n < 8; ++n) {
            const int e = n * 16 + l4;
            f32x4 aR = {0, 0, 0, 0}, aZ = {0, 0, 0, 0}, aN = {0, 0, 0, 0};
#pragma unroll
            for (int kc = 0; kc < 4; ++kc) {
                half8 hh = *(const half8*)&h0hi[e][32 * kc + 8 * q];
                half8 hl = *(const half8*)&h0lo[e][32 * kc + 8 * q];
                aR = MFMA(wl0[0][kc], hh, aR);
                aZ = MFMA(wl0[1][kc], hh, aZ);
                aN = MFMA(wl0[2][kc], hh, aN);
                aR = MFMA(wl0[0][kc], hl, aR);
                aZ = MFMA(wl0[1][kc], hl, aZ);
                aN = MFMA(wl0[2][kc], hl, aN);
            }
            // epilogue: dims d0..d0+4 of element e
            f32x4 giR = {0, 0, 0, 0}, giZ = {0, 0, 0, 0}, giN = {0, 0, 0, 0};
            if (step > 0) {
                int pb = (int)((bmk[e] >> (step - 1)) & 1ull);
                const float* gp = &gi0T[pb][0][0];
                giR = *(const f32x4*)(gp + d0);
                giZ = *(const f32x4*)(gp + 128 + d0);
                giN = *(const f32x4*)(gp + 256 + d0);
            }
            half4 hph = *(const half4*)&h0hi[e][d0];
            half4 hpl = *(const half4*)&h0lo[e][d0];
            half4 nh, nl;
#pragma unroll
            for (int r = 0; r < 4; ++r) {
                float rr = sigmoid_f(giR[r] + aR[r]);
                float zz = sigmoid_f(giZ[r] + aZ[r]);
                float nn = tanh_f(giN[r] + rr * aN[r]);
                float hprev = (float)hph[r] + (float)hpl[r];
                float hn = (1.0f - zz) * nn + zz * hprev;
                _Float16 hi = (_Float16)hn;
                nh[r] = hi;
                nl[r] = (_Float16)(hn - (float)hi);
            }
            sh[n] = nh; sl[n] = nl;
        }
        __syncthreads();   // all layer-0 reads of h0 done
#pragma unroll
        for (int n = 0; n < 8; ++n) {
            *(half4*)&h0hi[n * 16 + l4][d0] = sh[n];
            *(half4*)&h0lo[n * 16 + l4][d0] = sl[n];
        }
        __syncthreads();   // h0 new visible

        // ===== Layer 1: K = [h0 (kc<4) ; h1 (kc>=4)], N-gate split =====
#pragma unroll
        for (int n = 0; n < 8; ++n) {
            const int e = n * 16 + l4;
            f32x4 aR = {0, 0, 0, 0}, aZ = {0, 0, 0, 0};
            f32x4 aNi = {0, 0, 0, 0}, aNh = {0, 0, 0, 0};
#pragma unroll
            for (int kc = 0; kc < 8; ++kc) {
                half8 hh, hl;
                if (kc < 4) {
                    hh = *(const half8*)&h0hi[e][32 * kc + 8 * q];
                    hl = *(const half8*)&h0lo[e][32 * kc + 8 * q];
                } else {
                    hh = *(const half8*)&h1hi[e][32 * (kc - 4) + 8 * q];
                    hl = *(const half8*)&h1lo[e][32 * (kc - 4) + 8 * q];
                }
                aR = MFMA(wl1[0][kc], hh, aR);
                aZ = MFMA(wl1[1][kc], hh, aZ);
                aR = MFMA(wl1[0][kc], hl, aR);
                aZ = MFMA(wl1[1][kc], hl, aZ);
                if (kc < 4) {
                    aNi = MFMA(wl1[2][kc], hh, aNi);
                    aNi = MFMA(wl1[2][kc], hl, aNi);
                } else {
                    aNh = MFMA(wl1[2][kc], hh, aNh);
                    aNh = MFMA(wl1[2][kc], hl, aNh);
                }
            }
            half4 hph = *(const half4*)&h1hi[e][d0];
            half4 hpl = *(const half4*)&h1lo[e][d0];
            float l0p = 0.0f, l1p = 0.0f;
            half4 nh, nl;
#pragma unroll
            for (int r = 0; r < 4; ++r) {
                float rr = sigmoid_f(aR[r]);
                float zz = sigmoid_f(aZ[r]);
                float nn = tanh_f(aNi[r] + rr * aNh[r]);
                float hprev = (float)hph[r] + (float)hpl[r];
                float hn = (1.0f - zz) * nn + zz * hprev;
                l0p = fmaf(hn, wlin0[r], l0p);
                l1p = fmaf(hn, wlin1[r], l1p);
                _Float16 hi = (_Float16)hn;
                nh[r] = hi;
                nl[r] = (_Float16)(hn - (float)hi);
            }
            sh[n] = nh; sl[n] = nl;
            // per-element partial logits over this wave's 16 dims (reduce over q)
            l0p += __shfl_xor(l0p, 16); l0p += __shfl_xor(l0p, 32);
            l1p += __shfl_xor(l1p, 16); l1p += __shfl_xor(l1p, 32);
            if (q == 0) { lsc[0][e][wv] = l0p; lsc[1][e][wv] = l1p; }
        }
        __syncthreads();   // all layer-1 reads of h0/h1 + lsc writes done
#pragma unroll
        for (int n = 0; n < 8; ++n) {
            *(half4*)&h1hi[n * 16 + l4][d0] = sh[n];
            *(half4*)&h1lo[n * 16 + l4][d0] = sl[n];
        }

        // ================= head (element eh, replicated across q) =================
        {
            f32x4 a0 = *(const f32x4*)&lsc[0][eh][0];
            f32x4 a1 = *(const f32x4*)&lsc[0][eh][4];
            f32x4 b0 = *(const f32x4*)&lsc[1][eh][0];
            f32x4 b1 = *(const f32x4*)&lsc[1][eh][4];
            float l0 = a0[0] + a0[1] + a0[2] + a0[3] + a1[0] + a1[1] + a1[2] + a1[3] + bl0;
            float l1 = b0[0] + b0[1] + b0[2] + b0[3] + b1[0] + b1[1] + b1[2] + b1[3] + bl1;

            float p0 = sigmoid_f(l0 - l1);
            float p1 = sigmoid_f(l1 - l0);
            float y0 = sqrtf(p0), y1 = sqrtf(p1);
            float ph0 = PI_F * l0 * rcp_fast(1.0f + fabsf(l0));
            float ph1 = PI_F * l1 * rcp_fast(1.0f + fabsf(l1));

            int bit = (int)((bmk[eh] >> step) & 1ull);
            bool is_even = (step & 1) == 0;
            float num   = is_even ? nu : nd;
            float lower = -16.0f + (float)(step >> 1);
            float occ   = (num < 16.0f) ? 1.0f : 0.0f;
            float unocc = (num > lower) ? 1.0f : 0.0f;
            if (step >= 16) {
                float m0 = y0 * unocc, m1 = y1 * occ;
                float nrm = fmaxf(sqrtf(m0 * m0 + m1 * m1), 1e-12f);
                float rn  = rcp_fast(nrm);
                y0 = m0 * rn; y1 = m1 * rn;
            }
            if (is_even) nu += (float)bit; else nd += (float)bit;
            amp *= bit ? y1 : y0;
            phs += bit ? ph1 : ph0;
        }
        __syncthreads();   // h1 new + lsc consumption complete before next step
    }

    if (q == 0) {
        int eg = eb + eh;
        if (eg < nbatch) {
            float s, c;
            sincosf(phs, &s, &c);
            out[eg]          = amp * c;
            out[nbatch + eg] = amp * s;
        }
    }
}

extern "C" void kernel_launch(void* const* d_in, const int* in_sizes, int n_in,
                              void* d_out, int out_size, void* d_ws, size_t ws_size,
                              hipStream_t stream) {
    const int*   x     = (const int*)  d_in[0];
    const float* w_ih0 = (const float*)d_in[1];
    const float* w_hh0 = (const float*)d_in[2];
    const float* w_ih1 = (const float*)d_in[3];
    const float* w_hh1 = (const float*)d_in[4];
    const float* w_lin = (const float*)d_in[5];
    const float* b_lin = (const float*)d_in[6];
    float* out = (float*)d_out;
    _Float16* wsp = (_Float16*)d_ws;

    const int nbatch = in_sizes[0] / 64;

    prep_kernel<<<384, 256, 0, stream>>>(w_hh0, w_ih1, w_hh1, wsp);

    const int blocks = (nbatch + 127) / 128;
    rnn_wf_pers<<<blocks, 512, 0, stream>>>(x, w_ih0, w_lin, b_lin, wsp, out, nbatch);
}